// Round 1
// baseline (1940.453 us; speedup 1.0000x reference)
//
#include <hip/hip_runtime.h>

#define NBATCH 4
#define NPTS   4096
#define NP     (NBATCH*NPTS)   // 16384
#define KK     32

// ---------------- ws layout (float units) ----------------
static const size_t OFF_PTS  = 0;            // float4[NP]            65536 f
static const size_t OFF_PI   = 65536;        // int[NP*8*32]        4194304
static const size_t OFF_IDX  = 4259840;      // int[NP*32]           524288
static const size_t OFF_TSK  = 4784128;      // float[NP*64]        1048576
static const size_t OFF_TC   = 5832704;      // float[NP*64]
static const size_t OFF_TGA  = 6881280;      // float[NP*64]
static const size_t OFF_PREL = 7929856;      // float[64*12]
static const size_t OFF_PSK  = 7930624;      // float[64*128]
static const size_t OFF_PTA  = 7938816;      // float[4096*128]
static const size_t OFF_PTC  = 8463104;      // float[4096*128]
static const size_t OFF_PTGA = 8987392;      // float[4096*128]
static const size_t OFF_AFF  = 9511680;      // float[640]: s1 o1 s2 o2 s3 o3 s4 o4 s5 o5

__device__ __forceinline__ float bcast(float v, int l) {
  return __int_as_float(__builtin_amdgcn_readlane(__float_as_int(v), l));
}
__device__ __forceinline__ float wsum(float v) {
#pragma unroll
  for (int o = 32; o; o >>= 1) v += __shfl_xor(v, o, 64);
  return v;
}

// ---------------- 1: pts4 = (x,y,z,|p|^2) ----------------
__global__ __launch_bounds__(256,1) void k_prep(const float* __restrict__ x, float4* __restrict__ pts) {
  int g = blockIdx.x * 256 + threadIdx.x;          // 0..NP-1
  int b = g / NPTS, n = g % NPTS;
  float vx = x[(b*3+0)*NPTS + n];
  float vy = x[(b*3+1)*NPTS + n];
  float vz = x[(b*3+2)*NPTS + n];
  float sq = vx*vx + vy*vy + vz*vz;
  pts[g] = make_float4(vx, vy, vz, sq);
}

// ---------------- 2: partial kNN (candidates split 8 ways) ----------------
__global__ __launch_bounds__(256,1) void k_knn(const float4* __restrict__ pts, int* __restrict__ pi) {
  int blk = blockIdx.x;
  int batch  = blk >> 7;      // /128
  int sub    = blk & 127;
  int eighth = sub >> 4;
  int chunk  = sub & 15;
  int nl = chunk * 256 + threadIdx.x;
  int n  = batch * NPTS + nl;
  float4 me = pts[n];
  float dist[KK]; int idl[KK];
#pragma unroll
  for (int s = 0; s < KK; ++s) { dist[s] = __builtin_inff(); idl[s] = 0; }
  int m0 = eighth * 512;
#pragma unroll 2
  for (int m = m0; m < m0 + 512; ++m) {
    float4 p = pts[batch * NPTS + m];
    float dot = fmaf(me.x, p.x, fmaf(me.y, p.y, me.z * p.z));
    float d = fmaf(-2.f, dot, me.w + p.w);
    if (d < dist[KK-1]) {
      float dd = d; int di = m;
#pragma unroll
      for (int s = 0; s < KK; ++s) {
        bool c = dd < dist[s];
        float td = dist[s]; int ti = idl[s];
        dist[s] = c ? dd : td; idl[s] = c ? di : ti;
        dd = c ? td : dd;      di = c ? ti : di;
      }
    }
  }
  int base = (n * 8 + eighth) * KK;
#pragma unroll
  for (int s = 0; s < KK; ++s) pi[base + s] = idl[s];
}

// ---------------- 3: merge 8 partial lists -> final 32 ----------------
__global__ __launch_bounds__(256,1) void k_merge(const float4* __restrict__ pts,
                                                 const int* __restrict__ pi, int* __restrict__ idx) {
  int n = blockIdx.x * 256 + threadIdx.x;
  int batch = n / NPTS;
  float4 me = pts[n];
  float dist[KK]; int idl[KK];
#pragma unroll
  for (int s = 0; s < KK; ++s) {
    int i = pi[(n*8 + 0)*KK + s];
    float4 p = pts[batch*NPTS + i];
    float dot = fmaf(me.x, p.x, fmaf(me.y, p.y, me.z * p.z));
    dist[s] = fmaf(-2.f, dot, me.w + p.w);
    idl[s] = i;
  }
  for (int L = 1; L < 8; ++L) {
    for (int s = 0; s < KK; ++s) {
      int i = pi[(n*8 + L)*KK + s];
      float4 p = pts[batch*NPTS + i];
      float dot = fmaf(me.x, p.x, fmaf(me.y, p.y, me.z * p.z));
      float d = fmaf(-2.f, dot, me.w + p.w);
      if (d >= dist[KK-1]) break;   // partial list sorted ascending
      float dd = d; int di = i;
#pragma unroll
      for (int t = 0; t < KK; ++t) {
        bool c = dd < dist[t];
        float td = dist[t]; int ti = idl[t];
        dist[t] = c ? dd : td; idl[t] = c ? di : ti;
        dd = c ? td : dd;      di = c ? ti : di;
      }
    }
  }
#pragma unroll
  for (int s = 0; s < KK; ++s) idx[n*KK + s] = idl[s];
}

// ---------------- 4: rel moments (9) + nb_max + t_sk + t_sk stats ----------------
__global__ __launch_bounds__(256,1) void k_stats1(const float4* __restrict__ pts, const int* __restrict__ idx,
                                                  const float* __restrict__ Wsk, float* __restrict__ tsk,
                                                  float* __restrict__ prel, float* __restrict__ psk) {
  __shared__ float rsum[9], lsum[64], lss[64];
  if (threadIdx.x < 9)  rsum[threadIdx.x] = 0.f;
  if (threadIdx.x < 64) { lsum[threadIdx.x] = 0.f; lss[threadIdx.x] = 0.f; }
  __syncthreads();
  int lane = threadIdx.x & 63;
  int n = blockIdx.x * 256 + threadIdx.x;
  int batch = n / NPTS;
  float4 me = pts[n];
  float s0=0,s1=0,s2=0,m00=0,m01=0,m02=0,m11=0,m12=0,m22=0;
  float nx=-__builtin_inff(), ny=-__builtin_inff(), nz=-__builtin_inff();
  for (int j = 0; j < KK; ++j) {
    int i = idx[n*KK + j];
    float4 p = pts[batch*NPTS + i];
    float r0 = p.x - me.x, r1 = p.y - me.y, r2 = p.z - me.z;
    s0 += r0; s1 += r1; s2 += r2;
    m00 = fmaf(r0,r0,m00); m01 = fmaf(r0,r1,m01); m02 = fmaf(r0,r2,m02);
    m11 = fmaf(r1,r1,m11); m12 = fmaf(r1,r2,m12); m22 = fmaf(r2,r2,m22);
    nx = fmaxf(nx, p.x); ny = fmaxf(ny, p.y); nz = fmaxf(nz, p.z);
  }
  float vals[9] = {s0,s1,s2,m00,m01,m02,m11,m12,m22};
#pragma unroll
  for (int t = 0; t < 9; ++t) {
    float r = wsum(vals[t]);
    if (lane == 0) atomicAdd(&rsum[t], r);
  }
  for (int d = 0; d < 64; ++d) {
    const float* w = Wsk + d*6;
    float t = fmaf(me.x,w[0], fmaf(me.y,w[1], fmaf(me.z,w[2],
              fmaf(nx,w[3], fmaf(ny,w[4], nz*w[5])))));
    tsk[n*64 + d] = t;
    float rs = wsum(t), rq = wsum(t*t);
    if (lane == 0) { atomicAdd(&lsum[d], rs); atomicAdd(&lss[d], rq); }
  }
  __syncthreads();
  if (threadIdx.x < 9)  prel[blockIdx.x*12 + threadIdx.x] = rsum[threadIdx.x];
  if (threadIdx.x < 64) psk[blockIdx.x*128 + threadIdx.x] = lsum[threadIdx.x];
  else if (threadIdx.x < 128) psk[blockIdx.x*128 + threadIdx.x] = lss[threadIdx.x - 64];
}

// ---------------- 5: finalize BN1 (from rel moments) and BN_sk ----------------
__global__ __launch_bounds__(64,1) void k_fin1(const float* __restrict__ prel, const float* __restrict__ psk,
                                               const float* __restrict__ Wp1,
                                               const float* __restrict__ g_p, const float* __restrict__ b_p,
                                               const float* __restrict__ g_sk, const float* __restrict__ b_sk,
                                               float* __restrict__ aff) {
  int d = threadIdx.x;
  double S[9];
#pragma unroll
  for (int t = 0; t < 9; ++t) S[t] = 0.0;
  for (int r = 0; r < 64; ++r)
#pragma unroll
    for (int t = 0; t < 9; ++t) S[t] += (double)prel[r*12 + t];
  double C = (double)NP * (double)KK;
  double mr0 = S[0]/C, mr1 = S[1]/C, mr2 = S[2]/C;
  double e00 = S[3]/C, e01 = S[4]/C, e02 = S[5]/C, e11 = S[6]/C, e12 = S[7]/C, e22 = S[8]/C;
  double w0 = Wp1[d*3+0], w1 = Wp1[d*3+1], w2 = Wp1[d*3+2];
  double mu  = w0*mr0 + w1*mr1 + w2*mr2;
  double ex2 = w0*w0*e00 + w1*w1*e11 + w2*w2*e22 + 2.0*(w0*w1*e01 + w0*w2*e02 + w1*w2*e12);
  double var = ex2 - mu*mu;
  double sc  = (double)g_p[d] / sqrt(var + 1e-5);
  aff[0*64 + d] = (float)sc;
  aff[1*64 + d] = (float)((double)b_p[d] - mu*sc);
  // BN_sk (direct stats)
  double ss = 0.0, sq = 0.0;
  for (int r = 0; r < 64; ++r) { ss += (double)psk[r*128 + d]; sq += (double)psk[r*128 + 64 + d]; }
  double C2 = (double)NP;
  double mean = ss / C2, v2 = sq / C2 - mean*mean;
  double sc4 = (double)g_sk[d] / sqrt(v2 + 1e-5);
  aff[6*64 + d] = (float)sc4;
  aff[7*64 + d] = (float)((double)b_sk[d] - mean*sc4);
}

// ---------------- generic direct-stats finalize ----------------
__global__ __launch_bounds__(256,1) void k_fin_direct(const float* __restrict__ pblk, int nrows, double C,
                                                      const float* __restrict__ g, const float* __restrict__ b,
                                                      float* __restrict__ s_out, float* __restrict__ o_out) {
  __shared__ double lsum[4][64], lss[4][64];
  int d = threadIdx.x & 63, part = threadIdx.x >> 6;
  double s = 0.0, q = 0.0;
  for (int r = part; r < nrows; r += 4) { s += (double)pblk[r*128 + d]; q += (double)pblk[r*128 + 64 + d]; }
  lsum[part][d] = s; lss[part][d] = q;
  __syncthreads();
  if (threadIdx.x < 64) {
    double S = lsum[0][d] + lsum[1][d] + lsum[2][d] + lsum[3][d];
    double Q = lss[0][d] + lss[1][d] + lss[2][d] + lss[3][d];
    double mean = S / C, var = Q / C - mean*mean;
    double sc = (double)g[d] / sqrt(var + 1e-5);
    s_out[d] = (float)sc;
    o_out[d] = (float)((double)b[d] - mean*sc);
  }
}

// ---------------- entry chain: MODE 0 = t_a stats; MODE 1 = softmax/agg/t_c ----------------
template<int MODE>
__global__ __launch_bounds__(256,1) void k_entry(const float4* __restrict__ pts, const int* __restrict__ idx,
                                                 const float* __restrict__ Wq, const float* __restrict__ Wkv,
                                                 const float* __restrict__ Wp1, const float* __restrict__ Wp2,
                                                 const float* __restrict__ Wa, const float* __restrict__ Wc1,
                                                 const float* __restrict__ aff, float* __restrict__ pblk,
                                                 float* __restrict__ tc) {
  __shared__ float psum[64], pss[64];
  if (threadIdx.x < 64) { psum[threadIdx.x] = 0.f; pss[threadIdx.x] = 0.f; }
  __syncthreads();
  const int lane = threadIdx.x & 63;
  const int n = __builtin_amdgcn_readfirstlane(blockIdx.x * 4 + (threadIdx.x >> 6));
  const int batch = n >> 12;
  float w2[64], wa[64];
#pragma unroll
  for (int d = 0; d < 64; d += 4) {
    const float4 a = *(const float4*)(Wp2 + lane*64 + d);
    w2[d] = a.x; w2[d+1] = a.y; w2[d+2] = a.z; w2[d+3] = a.w;
    const float4 bb = *(const float4*)(Wa + lane*64 + d);
    wa[d] = bb.x; wa[d+1] = bb.y; wa[d+2] = bb.z; wa[d+3] = bb.w;
  }
  const float w1a = Wp1[lane*3+0], w1b = Wp1[lane*3+1], w1c = Wp1[lane*3+2];
  const float kfa = Wkv[lane*3+0], kfb = Wkv[lane*3+1], kfc = Wkv[lane*3+2];
  const float vfa = Wkv[(64+lane)*3+0], vfb = Wkv[(64+lane)*3+1], vfc = Wkv[(64+lane)*3+2];
  const float s1 = aff[0 + lane], o1 = aff[64 + lane];
  float s2 = 0.f, o2 = 0.f;
  if (MODE == 1) { s2 = aff[128 + lane]; o2 = aff[192 + lane]; }
  const float4 me = pts[n];
  const float q = fmaf(me.x, Wq[lane*3+0], fmaf(me.y, Wq[lane*3+1], me.z * Wq[lane*3+2]));
  float sum = 0.f, ss = 0.f;
  float mrun = -__builtin_inff(), srun = 0.f, arun = 0.f;
  for (int j = 0; j < KK; ++j) {
    const int i = idx[n*KK + j];
    const float4 p = pts[batch*NPTS + i];
    const float r0 = p.x - me.x, r1 = p.y - me.y, r2 = p.z - me.z;
    const float tp = fmaf(r0, w1a, fmaf(r1, w1b, r2 * w1c));
    const float y = fmaxf(fmaf(tp, s1, o1), 0.f);
    float p0=0,p1=0,p2=0,p3=0;
#pragma unroll
    for (int d = 0; d < 64; d += 4) {
      p0 = fmaf(bcast(y, d+0), w2[d+0], p0);
      p1 = fmaf(bcast(y, d+1), w2[d+1], p1);
      p2 = fmaf(bcast(y, d+2), w2[d+2], p2);
      p3 = fmaf(bcast(y, d+3), w2[d+3], p3);
    }
    const float pos = (p0+p1) + (p2+p3);
    const float kf = fmaf(r0, kfa, fmaf(r1, kfb, r2 * kfc));
    const float u = (q - kf) + pos;
    float a0=0,a1=0,a2=0,a3=0;
#pragma unroll
    for (int d = 0; d < 64; d += 4) {
      a0 = fmaf(bcast(u, d+0), wa[d+0], a0);
      a1 = fmaf(bcast(u, d+1), wa[d+1], a1);
      a2 = fmaf(bcast(u, d+2), wa[d+2], a2);
      a3 = fmaf(bcast(u, d+3), wa[d+3], a3);
    }
    const float ta = (a0+a1) + (a2+a3);
    if (MODE == 0) {
      sum += ta; ss = fmaf(ta, ta, ss);
    } else {
      const float l = fmaxf(fmaf(ta, s2, o2), 0.f);
      const float vf = fmaf(r0, vfa, fmaf(r1, vfb, r2 * vfc));
      const float pv = vf + pos;
      const float mn = fmaxf(mrun, l);
      const float c = __expf(mrun - mn);
      const float t = __expf(l - mn);
      srun = fmaf(srun, c, t);
      arun = fmaf(arun, c, t * pv);
      mrun = mn;
    }
  }
  if (MODE == 0) {
    atomicAdd(&psum[lane], sum);
    atomicAdd(&pss[lane], ss);
  } else {
    const float agg = arun / srun;
    float t0=0,t1=0,t2=0,t3=0;
#pragma unroll
    for (int d = 0; d < 64; d += 4) {
      t0 = fmaf(bcast(agg, d+0), Wc1[lane*64 + d+0], t0);
      t1 = fmaf(bcast(agg, d+1), Wc1[lane*64 + d+1], t1);
      t2 = fmaf(bcast(agg, d+2), Wc1[lane*64 + d+2], t2);
      t3 = fmaf(bcast(agg, d+3), Wc1[lane*64 + d+3], t3);
    }
    const float tcv = (t0+t1) + (t2+t3);
    tc[n*64 + lane] = tcv;
    atomicAdd(&psum[lane], tcv);
    atomicAdd(&pss[lane], tcv * tcv);
  }
  __syncthreads();
  if (threadIdx.x < 64) pblk[blockIdx.x*128 + threadIdx.x] = psum[threadIdx.x];
  else if (threadIdx.x < 128) pblk[blockIdx.x*128 + threadIdx.x] = pss[threadIdx.x - 64];
}

// ---------------- t_ga = concat(h, sk) @ Wga^T + its stats ----------------
__global__ __launch_bounds__(256,1) void k_final(const float* __restrict__ tcb, const float* __restrict__ tskb,
                                                 const float* __restrict__ Wga, const float* __restrict__ aff,
                                                 float* __restrict__ tga, float* __restrict__ pblk) {
  __shared__ float psum[64], pss[64];
  if (threadIdx.x < 64) { psum[threadIdx.x] = 0.f; pss[threadIdx.x] = 0.f; }
  __syncthreads();
  const int lane = threadIdx.x & 63;
  const int n = blockIdx.x * 4 + (threadIdx.x >> 6);
  const float h  = fmaxf(fmaf(tcb[n*64 + lane],  aff[256 + lane], aff[320 + lane]), 0.f);
  const float sk = fmaxf(fmaf(tskb[n*64 + lane], aff[384 + lane], aff[448 + lane]), 0.f);
  float g0=0,g1=0,g2=0,g3=0;
#pragma unroll
  for (int d = 0; d < 64; d += 4) {
    g0 = fmaf(bcast(h, d+0), Wga[lane*128 + d+0], g0);
    g1 = fmaf(bcast(h, d+1), Wga[lane*128 + d+1], g1);
    g2 = fmaf(bcast(h, d+2), Wga[lane*128 + d+2], g2);
    g3 = fmaf(bcast(h, d+3), Wga[lane*128 + d+3], g3);
  }
#pragma unroll
  for (int d = 0; d < 64; d += 4) {
    g0 = fmaf(bcast(sk, d+0), Wga[lane*128 + 64 + d+0], g0);
    g1 = fmaf(bcast(sk, d+1), Wga[lane*128 + 64 + d+1], g1);
    g2 = fmaf(bcast(sk, d+2), Wga[lane*128 + 64 + d+2], g2);
    g3 = fmaf(bcast(sk, d+3), Wga[lane*128 + 64 + d+3], g3);
  }
  const float tg = (g0+g1) + (g2+g3);
  tga[n*64 + lane] = tg;
  atomicAdd(&psum[lane], tg);
  atomicAdd(&pss[lane], tg * tg);
  __syncthreads();
  if (threadIdx.x < 64) pblk[blockIdx.x*128 + threadIdx.x] = psum[threadIdx.x];
  else if (threadIdx.x < 128) pblk[blockIdx.x*128 + threadIdx.x] = pss[threadIdx.x - 64];
}

// ---------------- output: relu(BN5) + transpose to (B,64,N) ----------------
__global__ __launch_bounds__(256,1) void k_out(const float* __restrict__ tga, const float* __restrict__ aff,
                                               float* __restrict__ out) {
  int g = blockIdx.x * 256 + threadIdx.x;   // 0 .. B*64*N-1
  int nn = g & 4095;
  int e  = (g >> 12) & 63;
  int b  = g >> 18;
  float v = tga[((b << 12) + nn) * 64 + e];
  out[g] = fmaxf(fmaf(v, aff[512 + e], aff[576 + e]), 0.f);
}

extern "C" void kernel_launch(void* const* d_in, const int* in_sizes, int n_in,
                              void* d_out, int out_size, void* d_ws, size_t ws_size,
                              hipStream_t stream) {
  const float* x    = (const float*)d_in[0];
  const float* Wq   = (const float*)d_in[1];
  const float* Wkv  = (const float*)d_in[2];
  const float* Wp1  = (const float*)d_in[3];
  const float* Wp2  = (const float*)d_in[4];
  const float* Wa   = (const float*)d_in[5];
  const float* Wc1  = (const float*)d_in[6];
  const float* Wsk  = (const float*)d_in[7];
  const float* Wga  = (const float*)d_in[8];
  const float* g_p  = (const float*)d_in[9];
  const float* b_p  = (const float*)d_in[10];
  const float* g_a  = (const float*)d_in[11];
  const float* b_a  = (const float*)d_in[12];
  const float* g_c  = (const float*)d_in[13];
  const float* b_c  = (const float*)d_in[14];
  const float* g_sk = (const float*)d_in[15];
  const float* b_sk = (const float*)d_in[16];
  const float* g_ga = (const float*)d_in[17];
  const float* b_ga = (const float*)d_in[18];
  // d_in[19] = k, fixed at 32
  float* W = (float*)d_ws;
  float4* pts  = (float4*)(W + OFF_PTS);
  int*   pi    = (int*)(W + OFF_PI);
  int*   idx   = (int*)(W + OFF_IDX);
  float* tsk   = W + OFF_TSK;
  float* tc    = W + OFF_TC;
  float* tga   = W + OFF_TGA;
  float* prel  = W + OFF_PREL;
  float* psk   = W + OFF_PSK;
  float* pta   = W + OFF_PTA;
  float* ptc   = W + OFF_PTC;
  float* ptga  = W + OFF_PTGA;
  float* aff   = W + OFF_AFF;
  float* out   = (float*)d_out;

  k_prep<<<64, 256, 0, stream>>>(x, pts);
  k_knn<<<512, 256, 0, stream>>>(pts, pi);
  k_merge<<<64, 256, 0, stream>>>(pts, pi, idx);
  k_stats1<<<64, 256, 0, stream>>>(pts, idx, Wsk, tsk, prel, psk);
  k_fin1<<<1, 64, 0, stream>>>(prel, psk, Wp1, g_p, b_p, g_sk, b_sk, aff);
  k_entry<0><<<4096, 256, 0, stream>>>(pts, idx, Wq, Wkv, Wp1, Wp2, Wa, nullptr, aff, pta, nullptr);
  k_fin_direct<<<1, 256, 0, stream>>>(pta, 4096, (double)NP * (double)KK, g_a, b_a, aff + 128, aff + 192);
  k_entry<1><<<4096, 256, 0, stream>>>(pts, idx, Wq, Wkv, Wp1, Wp2, Wa, Wc1, aff, ptc, tc);
  k_fin_direct<<<1, 256, 0, stream>>>(ptc, 4096, (double)NP, g_c, b_c, aff + 256, aff + 320);
  k_final<<<4096, 256, 0, stream>>>(tc, tsk, Wga, aff, tga, ptga);
  k_fin_direct<<<1, 256, 0, stream>>>(ptga, 4096, (double)NP, g_ga, b_ga, aff + 512, aff + 576);
  k_out<<<4096, 256, 0, stream>>>(tga, aff, out);
}

// Round 2
// 1148.612 us; speedup vs baseline: 1.6894x; 1.6894x over previous
//
#include <hip/hip_runtime.h>

#define NBATCH 4
#define NPTS   4096
#define NP     (NBATCH*NPTS)   // 16384
#define KK     32
#define INF    __builtin_inff()
#define STKCAP 16

// ---------------- ws layout (float units) ----------------
static const size_t OFF_PTS  = 0;            // float4[NP]
static const size_t OFF_PI   = 65536;        // int[NP*8*32]
static const size_t OFF_IDX  = 4259840;      // int[NP*32]
static const size_t OFF_TSK  = 4784128;      // float[NP*64]
static const size_t OFF_TC   = 5832704;      // float[NP*64]
static const size_t OFF_TGA  = 6881280;      // float[NP*64]
static const size_t OFF_PREL = 7929856;      // float[64*12]
static const size_t OFF_PSK  = 7930624;      // float[64*128]
static const size_t OFF_PTA  = 7938816;      // float[128]
static const size_t OFF_PTC  = 7938944;      // float[128]
static const size_t OFF_PTGA = 7939072;      // float[128]
static const size_t OFF_AFF  = 7939200;      // float[640]

__device__ __forceinline__ float wsum(float v) {
#pragma unroll
  for (int o = 32; o; o >>= 1) v += __shfl_xor(v, o, 64);
  return v;
}

// ---------------- 1: pts4 = (x,y,z,|p|^2) + zero stat accumulators ----------------
__global__ __launch_bounds__(256,1) void k_prep(const float* __restrict__ x, float4* __restrict__ pts,
                                                float* __restrict__ pta, float* __restrict__ ptc,
                                                float* __restrict__ ptga) {
  if (blockIdx.x == 0 && threadIdx.x < 128) {
    pta[threadIdx.x] = 0.f; ptc[threadIdx.x] = 0.f; ptga[threadIdx.x] = 0.f;
  }
  int g = blockIdx.x * 256 + threadIdx.x;
  int b = g / NPTS, n = g % NPTS;
  float vx = x[(b*3+0)*NPTS + n];
  float vy = x[(b*3+1)*NPTS + n];
  float vz = x[(b*3+2)*NPTS + n];
  pts[g] = make_float4(vx, vy, vz, vx*vx + vy*vy + vz*vz);
}

// ---------------- 2: partial kNN with LDS hit-buffer (split 8 over candidates) ----------------
__global__ __launch_bounds__(256,1) void k_knn(const float4* __restrict__ pts, int* __restrict__ pi) {
  __shared__ float2 stk[STKCAP][256];      // lane-major: divergent slot -> 2-way alias (free)
  int blk = blockIdx.x;
  int batch  = blk >> 7;
  int sub    = blk & 127;
  int eighth = sub >> 4;
  int chunk  = sub & 15;
  int nl = chunk * 256 + threadIdx.x;
  int n  = batch * NPTS + nl;
  const float4* base = pts + batch * NPTS;
  float4 me = pts[n];
  float dist[KK]; int idl[KK];
#pragma unroll
  for (int s = 0; s < KK; ++s) { dist[s] = INF; idl[s] = 0; }
  float kmax = INF;
  int cnt = 0;

  auto drain = [&]() {
    for (int j = 0; j < cnt; ++j) {
      float2 e = stk[j][threadIdx.x];
      float dd = e.x;
      if (dd < dist[KK-1]) {
        int di = __float_as_int(e.y);
#pragma unroll
        for (int s = 0; s < KK; ++s) {
          bool c = dd < dist[s];
          float td = dist[s]; int ti = idl[s];
          dist[s] = c ? dd : td; idl[s] = c ? di : ti;
          dd = c ? td : dd;      di = c ? ti : di;
        }
      }
    }
    cnt = 0;
    kmax = dist[KK-1];
  };

  int m0 = eighth * 512;
  float4 p = base[m0];
  for (int m = m0; m < m0 + 512; ++m) {
    float4 pn = base[m + 1];   // one-past-chunk read stays inside ws (harmless)
    float dot = fmaf(me.x, p.x, fmaf(me.y, p.y, me.z * p.z));
    float d = fmaf(-2.f, dot, me.w + p.w);
    if (d < kmax) {
      stk[cnt][threadIdx.x] = make_float2(d, __int_as_float(m));
      ++cnt;
    }
    if (__any(cnt == STKCAP)) drain();
    p = pn;
  }
  drain();

  int bout = (n * 8 + eighth) * KK;
#pragma unroll
  for (int s = 0; s < KK; ++s) pi[bout + s] = idl[s];
}

// ---------------- 3: merge 8 partial lists + rel-moments + nb_max + t_sk stats ----------------
__global__ __launch_bounds__(256,1) void k_merge2(const float4* __restrict__ pts, const int* __restrict__ pi,
                                                  const float* __restrict__ Wsk, int* __restrict__ idx,
                                                  float* __restrict__ tsk, float* __restrict__ prel,
                                                  float* __restrict__ psk) {
  __shared__ float rsum[9], lsum[64], lss[64];
  if (threadIdx.x < 9)  rsum[threadIdx.x] = 0.f;
  if (threadIdx.x < 64) { lsum[threadIdx.x] = 0.f; lss[threadIdx.x] = 0.f; }
  __syncthreads();
  int lane = threadIdx.x & 63;
  int n = blockIdx.x * 256 + threadIdx.x;
  int batch = n / NPTS;
  const float4* base = pts + batch * NPTS;
  float4 me = pts[n];
  float dist[KK]; int idl[KK];
#pragma unroll
  for (int s = 0; s < KK; ++s) {
    int i = pi[(n*8 + 0)*KK + s];
    float4 p = base[i];
    float dot = fmaf(me.x, p.x, fmaf(me.y, p.y, me.z * p.z));
    dist[s] = fmaf(-2.f, dot, me.w + p.w);
    idl[s] = i;
  }
  for (int L = 1; L < 8; ++L) {
    for (int s = 0; s < KK; ++s) {
      int i = pi[(n*8 + L)*KK + s];
      float4 p = base[i];
      float dot = fmaf(me.x, p.x, fmaf(me.y, p.y, me.z * p.z));
      float d = fmaf(-2.f, dot, me.w + p.w);
      if (d >= dist[KK-1]) break;   // partial lists sorted ascending
      float dd = d; int di = i;
#pragma unroll
      for (int t = 0; t < KK; ++t) {
        bool c = dd < dist[t];
        float td = dist[t]; int ti = idl[t];
        dist[t] = c ? dd : td; idl[t] = c ? di : ti;
        dd = c ? td : dd;      di = c ? ti : di;
      }
    }
  }
#pragma unroll
  for (int s = 0; s < KK; ++s) idx[n*KK + s] = idl[s];

  // ---- stats over final neighbor list ----
  float s0=0,s1=0,s2=0,m00=0,m01=0,m02=0,m11=0,m12=0,m22=0;
  float nx=-INF, ny=-INF, nz=-INF;
  for (int j = 0; j < KK; ++j) {
    float4 p = base[idl[j]];
    float r0 = p.x - me.x, r1 = p.y - me.y, r2 = p.z - me.z;
    s0 += r0; s1 += r1; s2 += r2;
    m00 = fmaf(r0,r0,m00); m01 = fmaf(r0,r1,m01); m02 = fmaf(r0,r2,m02);
    m11 = fmaf(r1,r1,m11); m12 = fmaf(r1,r2,m12); m22 = fmaf(r2,r2,m22);
    nx = fmaxf(nx, p.x); ny = fmaxf(ny, p.y); nz = fmaxf(nz, p.z);
  }
  float vals[9] = {s0,s1,s2,m00,m01,m02,m11,m12,m22};
#pragma unroll
  for (int t = 0; t < 9; ++t) {
    float r = wsum(vals[t]);
    if (lane == 0) atomicAdd(&rsum[t], r);
  }
  for (int d = 0; d < 64; ++d) {
    const float* w = Wsk + d*6;
    float t = fmaf(me.x,w[0], fmaf(me.y,w[1], fmaf(me.z,w[2],
              fmaf(nx,w[3], fmaf(ny,w[4], nz*w[5])))));
    tsk[n*64 + d] = t;
    float rs = wsum(t), rq = wsum(t*t);
    if (lane == 0) { atomicAdd(&lsum[d], rs); atomicAdd(&lss[d], rq); }
  }
  __syncthreads();
  if (threadIdx.x < 9)  prel[blockIdx.x*12 + threadIdx.x] = rsum[threadIdx.x];
  if (threadIdx.x < 64) psk[blockIdx.x*128 + threadIdx.x] = lsum[threadIdx.x];
  else if (threadIdx.x < 128) psk[blockIdx.x*128 + threadIdx.x] = lss[threadIdx.x - 64];
}

// ---------------- 4: finalize BN1 (from rel moments) and BN_sk ----------------
__global__ __launch_bounds__(64,1) void k_fin1(const float* __restrict__ prel, const float* __restrict__ psk,
                                               const float* __restrict__ Wp1,
                                               const float* __restrict__ g_p, const float* __restrict__ b_p,
                                               const float* __restrict__ g_sk, const float* __restrict__ b_sk,
                                               float* __restrict__ aff) {
  int d = threadIdx.x;
  double S[9];
#pragma unroll
  for (int t = 0; t < 9; ++t) S[t] = 0.0;
  for (int r = 0; r < 64; ++r)
#pragma unroll
    for (int t = 0; t < 9; ++t) S[t] += (double)prel[r*12 + t];
  double C = (double)NP * (double)KK;
  double mr0 = S[0]/C, mr1 = S[1]/C, mr2 = S[2]/C;
  double e00 = S[3]/C, e01 = S[4]/C, e02 = S[5]/C, e11 = S[6]/C, e12 = S[7]/C, e22 = S[8]/C;
  double w0 = Wp1[d*3+0], w1 = Wp1[d*3+1], w2 = Wp1[d*3+2];
  double mu  = w0*mr0 + w1*mr1 + w2*mr2;
  double ex2 = w0*w0*e00 + w1*w1*e11 + w2*w2*e22 + 2.0*(w0*w1*e01 + w0*w2*e02 + w1*w2*e12);
  double var = ex2 - mu*mu;
  double sc  = (double)g_p[d] / sqrt(var + 1e-5);
  aff[0*64 + d] = (float)sc;
  aff[1*64 + d] = (float)((double)b_p[d] - mu*sc);
  double ss = 0.0, sq = 0.0;
  for (int r = 0; r < 64; ++r) { ss += (double)psk[r*128 + d]; sq += (double)psk[r*128 + 64 + d]; }
  double C2 = (double)NP;
  double mean = ss / C2, v2 = sq / C2 - mean*mean;
  double sc4 = (double)g_sk[d] / sqrt(v2 + 1e-5);
  aff[6*64 + d] = (float)sc4;
  aff[7*64 + d] = (float)((double)b_sk[d] - mean*sc4);
}

// ---------------- tiny finalize from 128-word global accumulator ----------------
__global__ __launch_bounds__(64,1) void k_fin2(const float* __restrict__ st, double C,
                                               const float* __restrict__ g, const float* __restrict__ b,
                                               float* __restrict__ s_out, float* __restrict__ o_out) {
  int d = threadIdx.x;
  double mean = (double)st[d] / C;
  double var  = (double)st[64 + d] / C - mean*mean;
  double sc   = (double)g[d] / sqrt(var + 1e-5);
  s_out[d] = (float)sc;
  o_out[d] = (float)((double)b[d] - mean*sc);
}

// ---------------- entry chain: MODE 0 = t_a stats; MODE 1 = softmax/agg/t_c ----------------
template<int MODE>
__global__ __launch_bounds__(256,1) void k_entry(const float4* __restrict__ pts, const int* __restrict__ idx,
                                                 const float* __restrict__ Wq, const float* __restrict__ Wkv,
                                                 const float* __restrict__ Wp1, const float* __restrict__ Wp2,
                                                 const float* __restrict__ Wa, const float* __restrict__ Wc1,
                                                 const float* __restrict__ aff, float* __restrict__ pstats,
                                                 float* __restrict__ tc) {
  __shared__ __align__(16) float ybuf[4][64];
  __shared__ __align__(16) float ubuf[4][64];
  __shared__ float psum[64], pss[64];
  if (threadIdx.x < 64) { psum[threadIdx.x] = 0.f; pss[threadIdx.x] = 0.f; }
  __syncthreads();
  const int lane = threadIdx.x & 63;
  const int w    = threadIdx.x >> 6;
  const int n = blockIdx.x * 4 + w;
  const int batch = n >> 12;
  float w2[64], wa[64];
#pragma unroll
  for (int d = 0; d < 64; d += 4) {
    const float4 a = *(const float4*)(Wp2 + lane*64 + d);
    w2[d] = a.x; w2[d+1] = a.y; w2[d+2] = a.z; w2[d+3] = a.w;
    const float4 bb = *(const float4*)(Wa + lane*64 + d);
    wa[d] = bb.x; wa[d+1] = bb.y; wa[d+2] = bb.z; wa[d+3] = bb.w;
  }
  const float w1a = Wp1[lane*3+0], w1b = Wp1[lane*3+1], w1c = Wp1[lane*3+2];
  const float kfa = Wkv[lane*3+0], kfb = Wkv[lane*3+1], kfc = Wkv[lane*3+2];
  const float vfa = Wkv[(64+lane)*3+0], vfb = Wkv[(64+lane)*3+1], vfc = Wkv[(64+lane)*3+2];
  const float s1 = aff[lane], o1 = aff[64 + lane];
  float s2 = 0.f, o2 = 0.f;
  if (MODE == 1) { s2 = aff[128 + lane]; o2 = aff[192 + lane]; }
  const float4 me = pts[n];
  const float q = fmaf(me.x, Wq[lane*3+0], fmaf(me.y, Wq[lane*3+1], me.z * Wq[lane*3+2]));
  float sum = 0.f, ss = 0.f;
  float mrun = -INF, srun = 0.f, arun = 0.f;
  for (int j = 0; j < KK; ++j) {
    const int i = idx[n*KK + j];
    const float4 p = pts[batch*NPTS + i];
    const float r0 = p.x - me.x, r1 = p.y - me.y, r2 = p.z - me.z;
    const float tp = fmaf(r0, w1a, fmaf(r1, w1b, r2 * w1c));
    ybuf[w][lane] = fmaxf(fmaf(tp, s1, o1), 0.f);   // wave-synchronous LDS broadcast
    float p0=0,p1=0,p2=0,p3=0;
#pragma unroll
    for (int d = 0; d < 64; d += 4) {
      const float4 yv = *(const float4*)&ybuf[w][d];
      p0 = fmaf(yv.x, w2[d+0], p0);
      p1 = fmaf(yv.y, w2[d+1], p1);
      p2 = fmaf(yv.z, w2[d+2], p2);
      p3 = fmaf(yv.w, w2[d+3], p3);
    }
    const float pos = (p0+p1) + (p2+p3);
    const float kf = fmaf(r0, kfa, fmaf(r1, kfb, r2 * kfc));
    ubuf[w][lane] = (q - kf) + pos;
    float a0=0,a1=0,a2=0,a3=0;
#pragma unroll
    for (int d = 0; d < 64; d += 4) {
      const float4 uv = *(const float4*)&ubuf[w][d];
      a0 = fmaf(uv.x, wa[d+0], a0);
      a1 = fmaf(uv.y, wa[d+1], a1);
      a2 = fmaf(uv.z, wa[d+2], a2);
      a3 = fmaf(uv.w, wa[d+3], a3);
    }
    const float ta = (a0+a1) + (a2+a3);
    if (MODE == 0) {
      sum += ta; ss = fmaf(ta, ta, ss);
    } else {
      const float l = fmaxf(fmaf(ta, s2, o2), 0.f);
      const float vf = fmaf(r0, vfa, fmaf(r1, vfb, r2 * vfc));
      const float pv = vf + pos;
      const float mn = fmaxf(mrun, l);
      const float c = __expf(mrun - mn);
      const float t = __expf(l - mn);
      srun = fmaf(srun, c, t);
      arun = fmaf(arun, c, t * pv);
      mrun = mn;
    }
  }
  if (MODE == 0) {
    atomicAdd(&psum[lane], sum);
    atomicAdd(&pss[lane], ss);
  } else {
    const float agg = arun / srun;
    ubuf[w][lane] = agg;
    float t0=0,t1=0,t2=0,t3=0;
#pragma unroll
    for (int d = 0; d < 64; d += 4) {
      const float4 uv = *(const float4*)&ubuf[w][d];
      const float4 wc = *(const float4*)(Wc1 + lane*64 + d);
      t0 = fmaf(uv.x, wc.x, t0);
      t1 = fmaf(uv.y, wc.y, t1);
      t2 = fmaf(uv.z, wc.z, t2);
      t3 = fmaf(uv.w, wc.w, t3);
    }
    const float tcv = (t0+t1) + (t2+t3);
    tc[n*64 + lane] = tcv;
    atomicAdd(&psum[lane], tcv);
    atomicAdd(&pss[lane], tcv * tcv);
  }
  __syncthreads();
  if (threadIdx.x < 64) atomicAdd(&pstats[threadIdx.x], psum[threadIdx.x]);
  else if (threadIdx.x < 128) atomicAdd(&pstats[threadIdx.x], pss[threadIdx.x - 64]);
}

// ---------------- t_ga = concat(h, sk) @ Wga^T + its stats ----------------
__global__ __launch_bounds__(256,1) void k_final(const float* __restrict__ tcb, const float* __restrict__ tskb,
                                                 const float* __restrict__ Wga, const float* __restrict__ aff,
                                                 float* __restrict__ tga, float* __restrict__ pstats) {
  __shared__ __align__(16) float hb[4][64];
  __shared__ __align__(16) float sb[4][64];
  __shared__ float psum[64], pss[64];
  if (threadIdx.x < 64) { psum[threadIdx.x] = 0.f; pss[threadIdx.x] = 0.f; }
  __syncthreads();
  const int lane = threadIdx.x & 63;
  const int w    = threadIdx.x >> 6;
  const int n = blockIdx.x * 4 + w;
  hb[w][lane] = fmaxf(fmaf(tcb[n*64 + lane],  aff[256 + lane], aff[320 + lane]), 0.f);
  sb[w][lane] = fmaxf(fmaf(tskb[n*64 + lane], aff[384 + lane], aff[448 + lane]), 0.f);
  float g0=0,g1=0,g2=0,g3=0;
#pragma unroll
  for (int d = 0; d < 64; d += 4) {
    const float4 hv = *(const float4*)&hb[w][d];
    const float4 wg = *(const float4*)(Wga + lane*128 + d);
    g0 = fmaf(hv.x, wg.x, g0);
    g1 = fmaf(hv.y, wg.y, g1);
    g2 = fmaf(hv.z, wg.z, g2);
    g3 = fmaf(hv.w, wg.w, g3);
  }
#pragma unroll
  for (int d = 0; d < 64; d += 4) {
    const float4 sv = *(const float4*)&sb[w][d];
    const float4 wg = *(const float4*)(Wga + lane*128 + 64 + d);
    g0 = fmaf(sv.x, wg.x, g0);
    g1 = fmaf(sv.y, wg.y, g1);
    g2 = fmaf(sv.z, wg.z, g2);
    g3 = fmaf(sv.w, wg.w, g3);
  }
  const float tg = (g0+g1) + (g2+g3);
  tga[n*64 + lane] = tg;
  atomicAdd(&psum[lane], tg);
  atomicAdd(&pss[lane], tg * tg);
  __syncthreads();
  if (threadIdx.x < 64) atomicAdd(&pstats[threadIdx.x], psum[threadIdx.x]);
  else if (threadIdx.x < 128) atomicAdd(&pstats[threadIdx.x], pss[threadIdx.x - 64]);
}

// ---------------- output: relu(BN5) + transpose to (B,64,N) ----------------
__global__ __launch_bounds__(256,1) void k_out(const float* __restrict__ tga, const float* __restrict__ aff,
                                               float* __restrict__ out) {
  int g = blockIdx.x * 256 + threadIdx.x;
  int nn = g & 4095;
  int e  = (g >> 12) & 63;
  int b  = g >> 18;
  float v = tga[((b << 12) + nn) * 64 + e];
  out[g] = fmaxf(fmaf(v, aff[512 + e], aff[576 + e]), 0.f);
}

extern "C" void kernel_launch(void* const* d_in, const int* in_sizes, int n_in,
                              void* d_out, int out_size, void* d_ws, size_t ws_size,
                              hipStream_t stream) {
  const float* x    = (const float*)d_in[0];
  const float* Wq   = (const float*)d_in[1];
  const float* Wkv  = (const float*)d_in[2];
  const float* Wp1  = (const float*)d_in[3];
  const float* Wp2  = (const float*)d_in[4];
  const float* Wa   = (const float*)d_in[5];
  const float* Wc1  = (const float*)d_in[6];
  const float* Wsk  = (const float*)d_in[7];
  const float* Wga  = (const float*)d_in[8];
  const float* g_p  = (const float*)d_in[9];
  const float* b_p  = (const float*)d_in[10];
  const float* g_a  = (const float*)d_in[11];
  const float* b_a  = (const float*)d_in[12];
  const float* g_c  = (const float*)d_in[13];
  const float* b_c  = (const float*)d_in[14];
  const float* g_sk = (const float*)d_in[15];
  const float* b_sk = (const float*)d_in[16];
  const float* g_ga = (const float*)d_in[17];
  const float* b_ga = (const float*)d_in[18];
  float* W = (float*)d_ws;
  float4* pts  = (float4*)(W + OFF_PTS);
  int*   pi    = (int*)(W + OFF_PI);
  int*   idx   = (int*)(W + OFF_IDX);
  float* tsk   = W + OFF_TSK;
  float* tc    = W + OFF_TC;
  float* tga   = W + OFF_TGA;
  float* prel  = W + OFF_PREL;
  float* psk   = W + OFF_PSK;
  float* pta   = W + OFF_PTA;
  float* ptc   = W + OFF_PTC;
  float* ptga  = W + OFF_PTGA;
  float* aff   = W + OFF_AFF;
  float* out   = (float*)d_out;

  k_prep<<<64, 256, 0, stream>>>(x, pts, pta, ptc, ptga);
  k_knn<<<512, 256, 0, stream>>>(pts, pi);
  k_merge2<<<64, 256, 0, stream>>>(pts, pi, Wsk, idx, tsk, prel, psk);
  k_fin1<<<1, 64, 0, stream>>>(prel, psk, Wp1, g_p, b_p, g_sk, b_sk, aff);
  k_entry<0><<<4096, 256, 0, stream>>>(pts, idx, Wq, Wkv, Wp1, Wp2, Wa, nullptr, aff, pta, nullptr);
  k_fin2<<<1, 64, 0, stream>>>(pta, (double)NP * (double)KK, g_a, b_a, aff + 128, aff + 192);
  k_entry<1><<<4096, 256, 0, stream>>>(pts, idx, Wq, Wkv, Wp1, Wp2, Wa, Wc1, aff, ptc, tc);
  k_fin2<<<1, 64, 0, stream>>>(ptc, (double)NP, g_c, b_c, aff + 256, aff + 320);
  k_final<<<4096, 256, 0, stream>>>(tc, tsk, Wga, aff, tga, ptga);
  k_fin2<<<1, 64, 0, stream>>>(ptga, (double)NP, g_ga, b_ga, aff + 512, aff + 576);
  k_out<<<4096, 256, 0, stream>>>(tga, aff, out);
}

// Round 3
// 677.317 us; speedup vs baseline: 2.8649x; 1.6958x over previous
//
#include <hip/hip_runtime.h>

#define NBATCH 4
#define NPTS   4096
#define NP     (NBATCH*NPTS)   // 16384
#define KK     32
#define INF    __builtin_inff()
#define STKCAP 16

// ---------------- ws layout (float units) ----------------
static const size_t OFF_PTS  = 0;            // float4[NP]
static const size_t OFF_PI   = 65536;        // int[NP*8*32]
static const size_t OFF_IDX  = 4259840;      // int[NP*32]
static const size_t OFF_TSK  = 4784128;      // float[NP*64]
static const size_t OFF_TC   = 5832704;      // float[NP*64]
static const size_t OFF_TGA  = 6881280;      // float[NP*64]
static const size_t OFF_PREL = 7929856;      // float[64*12]
static const size_t OFF_PSK  = 7930624;      // float[64*128]
static const size_t OFF_PTA  = 7938816;      // float[128]
static const size_t OFF_PTC  = 7938944;      // float[128]
static const size_t OFF_PTGA = 7939072;      // float[128]
static const size_t OFF_AFF  = 7939200;      // float[640]

typedef __bf16 bf16x8  __attribute__((ext_vector_type(8)));
typedef float  floatx16 __attribute__((ext_vector_type(16)));
#define MFMA32(a,b,c) __builtin_amdgcn_mfma_f32_32x32x16_bf16(a, b, c, 0, 0, 0)

union F8 { bf16x8 v; unsigned short us[8]; uint4 q4; };

__device__ __forceinline__ unsigned short bfbits(float f) {
  unsigned u = __float_as_uint(f);
  return (unsigned short)((u + 0x7FFFu + ((u >> 16) & 1u)) >> 16);
}
__device__ __forceinline__ floatx16 zero16() {
  floatx16 v;
#pragma unroll
  for (int i = 0; i < 16; ++i) v[i] = 0.f;
  return v;
}
__device__ __forceinline__ float wsum(float v) {
#pragma unroll
  for (int o = 32; o; o >>= 1) v += __shfl_xor(v, o, 64);
  return v;
}

// ---------------- 1: pts4 = (x,y,z,|p|^2) + zero stat accumulators ----------------
__global__ __launch_bounds__(256,1) void k_prep(const float* __restrict__ x, float4* __restrict__ pts,
                                                float* __restrict__ pta, float* __restrict__ ptc,
                                                float* __restrict__ ptga) {
  if (blockIdx.x == 0 && threadIdx.x < 128) {
    pta[threadIdx.x] = 0.f; ptc[threadIdx.x] = 0.f; ptga[threadIdx.x] = 0.f;
  }
  int g = blockIdx.x * 256 + threadIdx.x;
  int b = g / NPTS, n = g % NPTS;
  float vx = x[(b*3+0)*NPTS + n];
  float vy = x[(b*3+1)*NPTS + n];
  float vz = x[(b*3+2)*NPTS + n];
  pts[g] = make_float4(vx, vy, vz, vx*vx + vy*vy + vz*vz);
}

// ---------------- 2: partial kNN with LDS hit-buffer (split 8 over candidates) ----------------
__global__ __launch_bounds__(256,1) void k_knn(const float4* __restrict__ pts, int* __restrict__ pi) {
  __shared__ float2 stk[STKCAP][256];
  int blk = blockIdx.x;
  int batch  = blk >> 7;
  int sub    = blk & 127;
  int eighth = sub >> 4;
  int chunk  = sub & 15;
  int nl = chunk * 256 + threadIdx.x;
  int n  = batch * NPTS + nl;
  const float4* base = pts + batch * NPTS;
  float4 me = pts[n];
  float dist[KK]; int idl[KK];
#pragma unroll
  for (int s = 0; s < KK; ++s) { dist[s] = INF; idl[s] = 0; }
  float kmax = INF;
  int cnt = 0;

  auto drain = [&]() {
    for (int j = 0; j < cnt; ++j) {
      float2 e = stk[j][threadIdx.x];
      float dd = e.x;
      if (dd < dist[KK-1]) {
        int di = __float_as_int(e.y);
#pragma unroll
        for (int s = 0; s < KK; ++s) {
          bool c = dd < dist[s];
          float td = dist[s]; int ti = idl[s];
          dist[s] = c ? dd : td; idl[s] = c ? di : ti;
          dd = c ? td : dd;      di = c ? ti : di;
        }
      }
    }
    cnt = 0;
    kmax = dist[KK-1];
  };

  int m0 = eighth * 512;
  float4 p = base[m0];
  for (int m = m0; m < m0 + 512; ++m) {
    float4 pn = base[m + 1];
    float dot = fmaf(me.x, p.x, fmaf(me.y, p.y, me.z * p.z));
    float d = fmaf(-2.f, dot, me.w + p.w);
    if (d < kmax) {
      stk[cnt][threadIdx.x] = make_float2(d, __int_as_float(m));
      ++cnt;
    }
    if (__any(cnt == STKCAP)) drain();
    p = pn;
  }
  drain();

  int bout = (n * 8 + eighth) * KK;
#pragma unroll
  for (int s = 0; s < KK; ++s) pi[bout + s] = idl[s];
}

// ---------------- 3: merge 8 partial lists + rel-moments + nb_max + t_sk stats ----------------
__global__ __launch_bounds__(256,1) void k_merge2(const float4* __restrict__ pts, const int* __restrict__ pi,
                                                  const float* __restrict__ Wsk, int* __restrict__ idx,
                                                  float* __restrict__ tsk, float* __restrict__ prel,
                                                  float* __restrict__ psk) {
  __shared__ float rsum[9], lsum[64], lss[64];
  if (threadIdx.x < 9)  rsum[threadIdx.x] = 0.f;
  if (threadIdx.x < 64) { lsum[threadIdx.x] = 0.f; lss[threadIdx.x] = 0.f; }
  __syncthreads();
  int lane = threadIdx.x & 63;
  int n = blockIdx.x * 256 + threadIdx.x;
  int batch = n / NPTS;
  const float4* base = pts + batch * NPTS;
  float4 me = pts[n];
  float dist[KK]; int idl[KK];
#pragma unroll
  for (int s = 0; s < KK; ++s) {
    int i = pi[(n*8 + 0)*KK + s];
    float4 p = base[i];
    float dot = fmaf(me.x, p.x, fmaf(me.y, p.y, me.z * p.z));
    dist[s] = fmaf(-2.f, dot, me.w + p.w);
    idl[s] = i;
  }
  for (int L = 1; L < 8; ++L) {
    for (int s = 0; s < KK; ++s) {
      int i = pi[(n*8 + L)*KK + s];
      float4 p = base[i];
      float dot = fmaf(me.x, p.x, fmaf(me.y, p.y, me.z * p.z));
      float d = fmaf(-2.f, dot, me.w + p.w);
      if (d >= dist[KK-1]) break;
      float dd = d; int di = i;
#pragma unroll
      for (int t = 0; t < KK; ++t) {
        bool c = dd < dist[t];
        float td = dist[t]; int ti = idl[t];
        dist[t] = c ? dd : td; idl[t] = c ? di : ti;
        dd = c ? td : dd;      di = c ? ti : di;
      }
    }
  }
#pragma unroll
  for (int s = 0; s < KK; ++s) idx[n*KK + s] = idl[s];

  float s0=0,s1=0,s2=0,m00=0,m01=0,m02=0,m11=0,m12=0,m22=0;
  float nx=-INF, ny=-INF, nz=-INF;
  for (int j = 0; j < KK; ++j) {
    float4 p = base[idl[j]];
    float r0 = p.x - me.x, r1 = p.y - me.y, r2 = p.z - me.z;
    s0 += r0; s1 += r1; s2 += r2;
    m00 = fmaf(r0,r0,m00); m01 = fmaf(r0,r1,m01); m02 = fmaf(r0,r2,m02);
    m11 = fmaf(r1,r1,m11); m12 = fmaf(r1,r2,m12); m22 = fmaf(r2,r2,m22);
    nx = fmaxf(nx, p.x); ny = fmaxf(ny, p.y); nz = fmaxf(nz, p.z);
  }
  float vals[9] = {s0,s1,s2,m00,m01,m02,m11,m12,m22};
#pragma unroll
  for (int t = 0; t < 9; ++t) {
    float r = wsum(vals[t]);
    if (lane == 0) atomicAdd(&rsum[t], r);
  }
  for (int d = 0; d < 64; ++d) {
    const float* w = Wsk + d*6;
    float t = fmaf(me.x,w[0], fmaf(me.y,w[1], fmaf(me.z,w[2],
              fmaf(nx,w[3], fmaf(ny,w[4], nz*w[5])))));
    tsk[n*64 + d] = t;
    float rs = wsum(t), rq = wsum(t*t);
    if (lane == 0) { atomicAdd(&lsum[d], rs); atomicAdd(&lss[d], rq); }
  }
  __syncthreads();
  if (threadIdx.x < 9)  prel[blockIdx.x*12 + threadIdx.x] = rsum[threadIdx.x];
  if (threadIdx.x < 64) psk[blockIdx.x*128 + threadIdx.x] = lsum[threadIdx.x];
  else if (threadIdx.x < 128) psk[blockIdx.x*128 + threadIdx.x] = lss[threadIdx.x - 64];
}

// ---------------- 4: finalize BN1 (from rel moments) and BN_sk ----------------
__global__ __launch_bounds__(64,1) void k_fin1(const float* __restrict__ prel, const float* __restrict__ psk,
                                               const float* __restrict__ Wp1,
                                               const float* __restrict__ g_p, const float* __restrict__ b_p,
                                               const float* __restrict__ g_sk, const float* __restrict__ b_sk,
                                               float* __restrict__ aff) {
  int d = threadIdx.x;
  double S[9];
#pragma unroll
  for (int t = 0; t < 9; ++t) S[t] = 0.0;
  for (int r = 0; r < 64; ++r)
#pragma unroll
    for (int t = 0; t < 9; ++t) S[t] += (double)prel[r*12 + t];
  double C = (double)NP * (double)KK;
  double mr0 = S[0]/C, mr1 = S[1]/C, mr2 = S[2]/C;
  double e00 = S[3]/C, e01 = S[4]/C, e02 = S[5]/C, e11 = S[6]/C, e12 = S[7]/C, e22 = S[8]/C;
  double w0 = Wp1[d*3+0], w1 = Wp1[d*3+1], w2 = Wp1[d*3+2];
  double mu  = w0*mr0 + w1*mr1 + w2*mr2;
  double ex2 = w0*w0*e00 + w1*w1*e11 + w2*w2*e22 + 2.0*(w0*w1*e01 + w0*w2*e02 + w1*w2*e12);
  double var = ex2 - mu*mu;
  double sc  = (double)g_p[d] / sqrt(var + 1e-5);
  aff[0*64 + d] = (float)sc;
  aff[1*64 + d] = (float)((double)b_p[d] - mu*sc);
  double ss = 0.0, sq = 0.0;
  for (int r = 0; r < 64; ++r) { ss += (double)psk[r*128 + d]; sq += (double)psk[r*128 + 64 + d]; }
  double C2 = (double)NP;
  double mean = ss / C2, v2 = sq / C2 - mean*mean;
  double sc4 = (double)g_sk[d] / sqrt(v2 + 1e-5);
  aff[6*64 + d] = (float)sc4;
  aff[7*64 + d] = (float)((double)b_sk[d] - mean*sc4);
}

// ---------------- tiny finalize from 128-word global accumulator ----------------
__global__ __launch_bounds__(64,1) void k_fin2(const float* __restrict__ st, double C,
                                               const float* __restrict__ g, const float* __restrict__ b,
                                               float* __restrict__ s_out, float* __restrict__ o_out) {
  int d = threadIdx.x;
  double mean = (double)st[d] / C;
  double var  = (double)st[64 + d] / C - mean*mean;
  double sc   = (double)g[d] / sqrt(var + 1e-5);
  s_out[d] = (float)sc;
  o_out[d] = (float)((double)b[d] - mean*sc);
}

// ---------------- MFMA entry chain: MODE 0 = t_a stats; MODE 1 = softmax/agg/t_c ----------------
// Per wave: 8 points. Per point: GEMM0 rel@Wp1T -> y (C-layout), GEMM1 [y|rel]@[W2T;-WkT / +WvT]
// (K=80, u-half & pv-half share pos mfmas), GEMM2 u@WaT. Softmax over j in C-layout.
template<int MODE>
__global__ __launch_bounds__(256,1) void k_entry(const float4* __restrict__ pts, const int* __restrict__ idx,
                                                 const float* __restrict__ Wq, const float* __restrict__ Wkv,
                                                 const float* __restrict__ Wp1, const float* __restrict__ Wp2,
                                                 const float* __restrict__ Wa, const float* __restrict__ Wc1,
                                                 const float* __restrict__ aff, float* __restrict__ pstats,
                                                 float* __restrict__ tc) {
  __shared__ __align__(16) unsigned short ybuf[4][32][72];   // rows j, cols d/e (pad 64->72)
  __shared__ __align__(16) float aggbuf[4][64];
  __shared__ float psum[64], pss[64];
  if (threadIdx.x < 64) { psum[threadIdx.x] = 0.f; pss[threadIdx.x] = 0.f; }
  __syncthreads();
  const int lane = threadIdx.x & 63;
  const int w    = threadIdx.x >> 6;
  const int c    = lane & 31;
  const int q5   = lane >> 5;

  // ---- B-fragments (per wave, reused across 8 points) ----
  F8 B0[2];                      // GEMM0: B[k][d]=Wp1[d][k] (k<3), d=nt*32+c
#pragma unroll
  for (int nt = 0; nt < 2; ++nt)
#pragma unroll
    for (int t = 0; t < 8; ++t)
      B0[nt].us[t] = (q5 == 0 && t < 3) ? bfbits(Wp1[(nt*32+c)*3 + t]) : (unsigned short)0;

  F8 Bs[4][2], B2[4][2];         // Bs: W2[e][d]; B2: Wa[e'][e]
#pragma unroll
  for (int kt = 0; kt < 4; ++kt)
#pragma unroll
    for (int h = 0; h < 2; ++h) {
      const float* p2 = Wp2 + (h*32+c)*64 + kt*16 + q5*8;
      float4 a = *(const float4*)p2, b = *(const float4*)(p2 + 4);
      Bs[kt][h].us[0]=bfbits(a.x); Bs[kt][h].us[1]=bfbits(a.y); Bs[kt][h].us[2]=bfbits(a.z); Bs[kt][h].us[3]=bfbits(a.w);
      Bs[kt][h].us[4]=bfbits(b.x); Bs[kt][h].us[5]=bfbits(b.y); Bs[kt][h].us[6]=bfbits(b.z); Bs[kt][h].us[7]=bfbits(b.w);
      const float* pa = Wa + (h*32+c)*64 + kt*16 + q5*8;
      float4 e = *(const float4*)pa, f = *(const float4*)(pa + 4);
      B2[kt][h].us[0]=bfbits(e.x); B2[kt][h].us[1]=bfbits(e.y); B2[kt][h].us[2]=bfbits(e.z); B2[kt][h].us[3]=bfbits(e.w);
      B2[kt][h].us[4]=bfbits(f.x); B2[kt][h].us[5]=bfbits(f.y); B2[kt][h].us[6]=bfbits(f.z); B2[kt][h].us[7]=bfbits(f.w);
    }

  F8 Bk4[4];                     // K-tail: nt<2 -> -Wk, nt>=2 -> +Wv
#pragma unroll
  for (int nt = 0; nt < 4; ++nt) {
    if (MODE == 0 && nt >= 2) { for (int t = 0; t < 8; ++t) Bk4[nt].us[t] = 0; continue; }
    int e = (nt & 1)*32 + c;
#pragma unroll
    for (int t = 0; t < 8; ++t)
      Bk4[nt].us[t] = (q5 == 0 && t < 3)
        ? bfbits(nt < 2 ? -Wkv[e*3 + t] : Wkv[(64+e)*3 + t]) : (unsigned short)0;
  }

  const float s1a = aff[c],      o1a = aff[64+c];
  const float s1b = aff[32+c],   o1b = aff[96+c];
  float s2a = 0.f, o2a = 0.f, s2b = 0.f, o2b = 0.f;
  if (MODE == 1) { s2a = aff[128+c]; o2a = aff[192+c]; s2b = aff[160+c]; o2b = aff[224+c]; }
  const float wqa0 = Wq[c*3+0],      wqa1 = Wq[c*3+1],      wqa2 = Wq[c*3+2];
  const float wqb0 = Wq[(32+c)*3+0], wqb1 = Wq[(32+c)*3+1], wqb2 = Wq[(32+c)*3+2];

  const int wave_id = blockIdx.x * 4 + w;
  const int n0 = wave_id * 8;
  const int batch = n0 >> 12;
  const float4* base = pts + batch * NPTS;

  for (int pi = 0; pi < 8; ++pi) {
    const int n = n0 + pi;
    const float4 me = pts[n];
    const int nb = idx[n*KK + c];
    const float4 pp = base[nb];
    const float r0 = pp.x - me.x, r1 = pp.y - me.y, r2 = pp.z - me.z;
    F8 relA;
#pragma unroll
    for (int t = 0; t < 8; ++t) relA.us[t] = 0;
    if (q5 == 0) { relA.us[0] = bfbits(r0); relA.us[1] = bfbits(r1); relA.us[2] = bfbits(r2); }

    const floatx16 z = zero16();
    floatx16 y0 = MFMA32(relA.v, B0[0].v, z);
    floatx16 y1 = MFMA32(relA.v, B0[1].v, z);
#pragma unroll
    for (int r = 0; r < 16; ++r) {
      int row = (r & 3) + 8*(r >> 2) + 4*q5;
      ybuf[w][row][c]      = bfbits(fmaxf(fmaf(y0[r], s1a, o1a), 0.f));
      ybuf[w][row][32 + c] = bfbits(fmaxf(fmaf(y1[r], s1b, o1b), 0.f));
    }
    F8 Ay[4];
#pragma unroll
    for (int kt = 0; kt < 4; ++kt) Ay[kt].q4 = *(const uint4*)&ybuf[w][c][kt*16 + q5*8];

    floatx16 Cp0 = z, Cp1 = z;
#pragma unroll
    for (int kt = 0; kt < 4; ++kt) {
      Cp0 = MFMA32(Ay[kt].v, Bs[kt][0].v, Cp0);
      Cp1 = MFMA32(Ay[kt].v, Bs[kt][1].v, Cp1);
    }
    floatx16 Cu0 = MFMA32(relA.v, Bk4[0].v, Cp0);   // pos - kf
    floatx16 Cu1 = MFMA32(relA.v, Bk4[1].v, Cp1);
    if (MODE == 1) {
      Cp0 = MFMA32(relA.v, Bk4[2].v, Cp0);          // pos + vf
      Cp1 = MFMA32(relA.v, Bk4[3].v, Cp1);
    }
    const float qa = fmaf(me.x, wqa0, fmaf(me.y, wqa1, me.z * wqa2));
    const float qb = fmaf(me.x, wqb0, fmaf(me.y, wqb1, me.z * wqb2));
#pragma unroll
    for (int r = 0; r < 16; ++r) {
      int row = (r & 3) + 8*(r >> 2) + 4*q5;
      ybuf[w][row][c]      = bfbits(Cu0[r] + qa);
      ybuf[w][row][32 + c] = bfbits(Cu1[r] + qb);
    }
    F8 Au[4];
#pragma unroll
    for (int kt = 0; kt < 4; ++kt) Au[kt].q4 = *(const uint4*)&ybuf[w][c][kt*16 + q5*8];
    floatx16 Ct0 = z, Ct1 = z;
#pragma unroll
    for (int kt = 0; kt < 4; ++kt) {
      Ct0 = MFMA32(Au[kt].v, B2[kt][0].v, Ct0);
      Ct1 = MFMA32(Au[kt].v, B2[kt][1].v, Ct1);
    }

    if (MODE == 0) {
      float sa = 0.f, qqa = 0.f, sb = 0.f, qqb = 0.f;
#pragma unroll
      for (int r = 0; r < 16; ++r) {
        sa += Ct0[r]; qqa = fmaf(Ct0[r], Ct0[r], qqa);
        sb += Ct1[r]; qqb = fmaf(Ct1[r], Ct1[r], qqb);
      }
      sa += __shfl_xor(sa, 32); qqa += __shfl_xor(qqa, 32);
      sb += __shfl_xor(sb, 32); qqb += __shfl_xor(qqb, 32);
      if (q5 == 0) {
        atomicAdd(&psum[c], sa);      atomicAdd(&pss[c], qqa);
        atomicAdd(&psum[32+c], sb);   atomicAdd(&pss[32+c], qqb);
      }
    } else {
      float ma = -INF, mb = -INF;
#pragma unroll
      for (int r = 0; r < 16; ++r) {
        float la = fmaxf(fmaf(Ct0[r], s2a, o2a), 0.f); Ct0[r] = la; ma = fmaxf(ma, la);
        float lb = fmaxf(fmaf(Ct1[r], s2b, o2b), 0.f); Ct1[r] = lb; mb = fmaxf(mb, lb);
      }
      ma = fmaxf(ma, __shfl_xor(ma, 32));
      mb = fmaxf(mb, __shfl_xor(mb, 32));
      float sa = 0.f, sb = 0.f, aga = 0.f, agb = 0.f;
#pragma unroll
      for (int r = 0; r < 16; ++r) {
        float ta = __expf(Ct0[r] - ma); sa += ta; aga = fmaf(ta, Cp0[r], aga);
        float tb = __expf(Ct1[r] - mb); sb += tb; agb = fmaf(tb, Cp1[r], agb);
      }
      sa += __shfl_xor(sa, 32); aga += __shfl_xor(aga, 32);
      sb += __shfl_xor(sb, 32); agb += __shfl_xor(agb, 32);
      if (q5 == 0) {
        aggbuf[w][c]      = aga / sa;
        aggbuf[w][32 + c] = agb / sb;
      }
      float acc = 0.f;
#pragma unroll
      for (int g = 0; g < 16; ++g) {
        float4 av = *(const float4*)&aggbuf[w][g*4];
        const float4 wv = *(const float4*)(Wc1 + lane*64 + g*4);
        acc = fmaf(av.x, wv.x, fmaf(av.y, wv.y, fmaf(av.z, wv.z, fmaf(av.w, wv.w, acc))));
      }
      tc[n*64 + lane] = acc;
      atomicAdd(&psum[lane], acc);
      atomicAdd(&pss[lane], acc * acc);
    }
  }
  __syncthreads();
  if (threadIdx.x < 64) atomicAdd(&pstats[threadIdx.x], psum[threadIdx.x]);
  else if (threadIdx.x < 128) atomicAdd(&pstats[threadIdx.x], pss[threadIdx.x - 64]);
}

// ---------------- t_ga = concat(h, sk) @ Wga^T + its stats ----------------
__global__ __launch_bounds__(256,1) void k_final(const float* __restrict__ tcb, const float* __restrict__ tskb,
                                                 const float* __restrict__ Wga, const float* __restrict__ aff,
                                                 float* __restrict__ tga, float* __restrict__ pstats) {
  __shared__ __align__(16) float hb[4][64];
  __shared__ __align__(16) float sb[4][64];
  __shared__ float psum[64], pss[64];
  if (threadIdx.x < 64) { psum[threadIdx.x] = 0.f; pss[threadIdx.x] = 0.f; }
  __syncthreads();
  const int lane = threadIdx.x & 63;
  const int w    = threadIdx.x >> 6;
  const int n = blockIdx.x * 4 + w;
  hb[w][lane] = fmaxf(fmaf(tcb[n*64 + lane],  aff[256 + lane], aff[320 + lane]), 0.f);
  sb[w][lane] = fmaxf(fmaf(tskb[n*64 + lane], aff[384 + lane], aff[448 + lane]), 0.f);
  float g0=0,g1=0,g2=0,g3=0;
#pragma unroll
  for (int d = 0; d < 64; d += 4) {
    const float4 hv = *(const float4*)&hb[w][d];
    const float4 wg = *(const float4*)(Wga + lane*128 + d);
    g0 = fmaf(hv.x, wg.x, g0);
    g1 = fmaf(hv.y, wg.y, g1);
    g2 = fmaf(hv.z, wg.z, g2);
    g3 = fmaf(hv.w, wg.w, g3);
  }
#pragma unroll
  for (int d = 0; d < 64; d += 4) {
    const float4 sv = *(const float4*)&sb[w][d];
    const float4 wg = *(const float4*)(Wga + lane*128 + 64 + d);
    g0 = fmaf(sv.x, wg.x, g0);
    g1 = fmaf(sv.y, wg.y, g1);
    g2 = fmaf(sv.z, wg.z, g2);
    g3 = fmaf(sv.w, wg.w, g3);
  }
  const float tg = (g0+g1) + (g2+g3);
  tga[n*64 + lane] = tg;
  atomicAdd(&psum[lane], tg);
  atomicAdd(&pss[lane], tg * tg);
  __syncthreads();
  if (threadIdx.x < 64) atomicAdd(&pstats[threadIdx.x], psum[threadIdx.x]);
  else if (threadIdx.x < 128) atomicAdd(&pstats[threadIdx.x], pss[threadIdx.x - 64]);
}

// ---------------- output: relu(BN5) + transpose to (B,64,N) ----------------
__global__ __launch_bounds__(256,1) void k_out(const float* __restrict__ tga, const float* __restrict__ aff,
                                               float* __restrict__ out) {
  int g = blockIdx.x * 256 + threadIdx.x;
  int nn = g & 4095;
  int e  = (g >> 12) & 63;
  int b  = g >> 18;
  float v = tga[((b << 12) + nn) * 64 + e];
  out[g] = fmaxf(fmaf(v, aff[512 + e], aff[576 + e]), 0.f);
}

extern "C" void kernel_launch(void* const* d_in, const int* in_sizes, int n_in,
                              void* d_out, int out_size, void* d_ws, size_t ws_size,
                              hipStream_t stream) {
  const float* x    = (const float*)d_in[0];
  const float* Wq   = (const float*)d_in[1];
  const float* Wkv  = (const float*)d_in[2];
  const float* Wp1  = (const float*)d_in[3];
  const float* Wp2  = (const float*)d_in[4];
  const float* Wa   = (const float*)d_in[5];
  const float* Wc1  = (const float*)d_in[6];
  const float* Wsk  = (const float*)d_in[7];
  const float* Wga  = (const float*)d_in[8];
  const float* g_p  = (const float*)d_in[9];
  const float* b_p  = (const float*)d_in[10];
  const float* g_a  = (const float*)d_in[11];
  const float* b_a  = (const float*)d_in[12];
  const float* g_c  = (const float*)d_in[13];
  const float* b_c  = (const float*)d_in[14];
  const float* g_sk = (const float*)d_in[15];
  const float* b_sk = (const float*)d_in[16];
  const float* g_ga = (const float*)d_in[17];
  const float* b_ga = (const float*)d_in[18];
  float* W = (float*)d_ws;
  float4* pts  = (float4*)(W + OFF_PTS);
  int*   pi    = (int*)(W + OFF_PI);
  int*   idx   = (int*)(W + OFF_IDX);
  float* tsk   = W + OFF_TSK;
  float* tc    = W + OFF_TC;
  float* tga   = W + OFF_TGA;
  float* prel  = W + OFF_PREL;
  float* psk   = W + OFF_PSK;
  float* pta   = W + OFF_PTA;
  float* ptc   = W + OFF_PTC;
  float* ptga  = W + OFF_PTGA;
  float* aff   = W + OFF_AFF;
  float* out   = (float*)d_out;

  k_prep<<<64, 256, 0, stream>>>(x, pts, pta, ptc, ptga);
  k_knn<<<512, 256, 0, stream>>>(pts, pi);
  k_merge2<<<64, 256, 0, stream>>>(pts, pi, Wsk, idx, tsk, prel, psk);
  k_fin1<<<1, 64, 0, stream>>>(prel, psk, Wp1, g_p, b_p, g_sk, b_sk, aff);
  k_entry<0><<<512, 256, 0, stream>>>(pts, idx, Wq, Wkv, Wp1, Wp2, Wa, nullptr, aff, pta, nullptr);
  k_fin2<<<1, 64, 0, stream>>>(pta, (double)NP * (double)KK, g_a, b_a, aff + 128, aff + 192);
  k_entry<1><<<512, 256, 0, stream>>>(pts, idx, Wq, Wkv, Wp1, Wp2, Wa, Wc1, aff, ptc, tc);
  k_fin2<<<1, 64, 0, stream>>>(ptc, (double)NP, g_c, b_c, aff + 256, aff + 320);
  k_final<<<4096, 256, 0, stream>>>(tc, tsk, Wga, aff, tga, ptga);
  k_fin2<<<1, 64, 0, stream>>>(ptga, (double)NP, g_ga, b_ga, aff + 512, aff + 576);
  k_out<<<4096, 256, 0, stream>>>(tga, aff, out);
}